// Round 1
// baseline (2031.724 us; speedup 1.0000x reference)
//
#include <hip/hip_runtime.h>
#include <cstdint>
#include <cstddef>

// GATv2 x2 layers. N=50000, E=800000, H=2, C_IN=256, C1=64, C2=128.
// Inputs (fp32 unless noted): x[N][256], edge_index int32 [2][E],
// Wl0[256][128], Wr0[256][128], att0[2][64], b0[128],
// Wl1[128][256], Wr1[128][256], att1[2][128], b1[256].
// Output fp32 [N][256].

#define NEG_SLOPE 0.2f

// ---------------------------------------------------------------------------
// C[M][2*NH] = A[M][K] @ [B1 | B2]  (B row-major [K][NH] each)
// 64x64 tile, BK=16, 4x4 per thread, 256 threads.
__global__ __launch_bounds__(256) void sgemm_dual(
    const float* __restrict__ A, const float* __restrict__ B1,
    const float* __restrict__ B2, float* __restrict__ C,
    int M, int K, int NH) {
  __shared__ float As[16][64];   // As[k][m]
  __shared__ float Bs[16][64];   // Bs[k][n]
  const int bn = blockIdx.x * 64;
  const int bm = blockIdx.y * 64;
  const float* __restrict__ B = (bn < NH) ? B1 : B2;
  const int bcol = (bn < NH) ? bn : (bn - NH);
  const int tid = threadIdx.x;
  const int tm = (tid >> 4) << 2;     // 0..60
  const int tn = (tid & 15) << 2;     // 0..60
  const int ar = tid >> 2;            // 0..63 (row within A tile)
  const int ac = (tid & 3) << 2;      // 0,4,8,12 (k within chunk)
  const int br = tid >> 4;            // 0..15 (k within chunk)
  const int bc = (tid & 15) << 2;     // 0..60 (col within tile)
  const bool aok = (bm + ar) < M;
  float acc[4][4] = {};
  for (int k0 = 0; k0 < K; k0 += 16) {
    float4 av = make_float4(0.f, 0.f, 0.f, 0.f);
    if (aok) av = *(const float4*)&A[(size_t)(bm + ar) * K + k0 + ac];
    const float4 bv = *(const float4*)&B[(size_t)(k0 + br) * NH + bcol + bc];
    __syncthreads();
    As[ac + 0][ar] = av.x; As[ac + 1][ar] = av.y;
    As[ac + 2][ar] = av.z; As[ac + 3][ar] = av.w;
    *(float4*)&Bs[br][bc] = bv;
    __syncthreads();
#pragma unroll
    for (int k = 0; k < 16; ++k) {
      const float4 a = *(const float4*)&As[k][tm];
      const float4 b = *(const float4*)&Bs[k][tn];
      acc[0][0] += a.x * b.x; acc[0][1] += a.x * b.y; acc[0][2] += a.x * b.z; acc[0][3] += a.x * b.w;
      acc[1][0] += a.y * b.x; acc[1][1] += a.y * b.y; acc[1][2] += a.y * b.z; acc[1][3] += a.y * b.w;
      acc[2][0] += a.z * b.x; acc[2][1] += a.z * b.y; acc[2][2] += a.z * b.z; acc[2][3] += a.z * b.w;
      acc[3][0] += a.w * b.x; acc[3][1] += a.w * b.y; acc[3][2] += a.w * b.z; acc[3][3] += a.w * b.w;
    }
  }
  const int NT = 2 * NH;
#pragma unroll
  for (int i = 0; i < 4; ++i) {
    const int r = bm + tm + i;
    if (r < M) {
      float4 o = make_float4(acc[i][0], acc[i][1], acc[i][2], acc[i][3]);
      *(float4*)&C[(size_t)r * NT + bn + tn] = o;
    }
  }
}

// ---------------------------------------------------------------------------
// Pass 1: one wave per (edge, head). logit = att . leaky_relu(xl[src]+xr[dst])
// feat row layout: [ xl_h0 | xl_h1 | xr_h0 | xr_h1 ], stride S = 4*C.
template <int C, int S>
__global__ __launch_bounds__(256) void edge_logit_max(
    const int* __restrict__ ei, int E, int EA,
    const float* __restrict__ feat, const float* __restrict__ att,
    float* __restrict__ alpha, unsigned int* __restrict__ mmax) {
  const int gt = blockIdx.x * blockDim.x + threadIdx.x;
  const int wid = gt >> 6;
  const int lane = threadIdx.x & 63;
  if (wid >= EA * 2) return;
  const int e = wid >> 1, h = wid & 1;
  int src, dst;
  if (e < E) { src = ei[e]; dst = ei[E + e]; } else { src = dst = e - E; }
  const float* __restrict__ pl = feat + (size_t)src * S + h * C;
  const float* __restrict__ pr = feat + (size_t)dst * S + 2 * C + h * C;
  const float* __restrict__ pa = att + h * C;
  float v = 0.f;
#pragma unroll
  for (int c = lane; c < C; c += 64) {
    float s = pl[c] + pr[c];
    s = (s > 0.f) ? s : NEG_SLOPE * s;
    v += s * pa[c];
  }
#pragma unroll
  for (int off = 32; off; off >>= 1) v += __shfl_down(v, off, 64);
  if (lane == 0) {
    alpha[wid] = v;
    unsigned int ub = __float_as_uint(v);
    ub = (ub >> 31) ? ~ub : (ub | 0x80000000u);
    atomicMax(&mmax[dst * 2 + h], ub);
  }
}

// Pass 2: a = exp(logit - m[dst]); denom[dst] += a
__global__ __launch_bounds__(256) void edge_expsum(
    const int* __restrict__ ei, int E, int EA,
    const unsigned int* __restrict__ mmax,
    float* __restrict__ alpha, float* __restrict__ denom) {
  const int t = blockIdx.x * blockDim.x + threadIdx.x;
  if (t >= EA * 2) return;
  const int e = t >> 1, h = t & 1;
  const int dst = (e < E) ? ei[E + e] : (e - E);
  const unsigned int u = mmax[dst * 2 + h];
  const unsigned int bits = (u >> 31) ? (u & 0x7fffffffu) : ~u;
  const float m = __uint_as_float(bits);
  const float a = expf(alpha[t] - m);
  alpha[t] = a;
  atomicAdd(&denom[dst * 2 + h], a);
}

// Pass 2b: alpha /= denom[dst]
__global__ __launch_bounds__(256) void alpha_norm(
    const int* __restrict__ ei, int E, int EA,
    const float* __restrict__ denom, float* __restrict__ alpha) {
  const int t = blockIdx.x * blockDim.x + threadIdx.x;
  if (t >= EA * 2) return;
  const int e = t >> 1, h = t & 1;
  const int dst = (e < E) ? ei[E + e] : (e - E);
  alpha[t] = alpha[t] / denom[dst * 2 + h];
}

// Pass 3: out[dst][c] += alpha * xl[src][c], thread per (edge, channel)
template <int C, int S, int SHIFT>
__global__ __launch_bounds__(256) void edge_scatter(
    const int* __restrict__ ei, int E, int EA,
    const float* __restrict__ feat, const float* __restrict__ alpha,
    float* __restrict__ out) {
  const int HC = 2 * C;
  const int t = blockIdx.x * blockDim.x + threadIdx.x;
  if (t >= EA * HC) return;            // EA*HC <= 217.6M < 2^31
  const int e = t >> SHIFT;
  const int c = t & (HC - 1);
  const int h = (c >= C) ? 1 : 0;
  int src, dst;
  if (e < E) { src = ei[e]; dst = ei[E + e]; } else { src = dst = e - E; }
  const float coef = alpha[e * 2 + h];
  atomicAdd(&out[(size_t)dst * HC + c], coef * feat[(size_t)src * S + c]);
}

// out[n][c] = b[c]
__global__ __launch_bounds__(256) void init_bias(
    float* __restrict__ out, const float* __restrict__ b, int total, int mask) {
  const int t = blockIdx.x * blockDim.x + threadIdx.x;
  if (t < total) out[t] = b[t & mask];
}

__global__ __launch_bounds__(256) void relu_inplace(float* __restrict__ p, int total) {
  const int t = blockIdx.x * blockDim.x + threadIdx.x;
  if (t < total) p[t] = fmaxf(p[t], 0.f);
}

// ---------------------------------------------------------------------------
extern "C" void kernel_launch(void* const* d_in, const int* in_sizes, int n_in,
                              void* d_out, int out_size, void* d_ws, size_t ws_size,
                              hipStream_t stream) {
  const float* x    = (const float*)d_in[0];
  const int*   ei   = (const int*)d_in[1];
  const float* Wl0  = (const float*)d_in[2];
  const float* Wr0  = (const float*)d_in[3];
  const float* att0 = (const float*)d_in[4];
  const float* b0   = (const float*)d_in[5];
  const float* Wl1  = (const float*)d_in[6];
  const float* Wr1  = (const float*)d_in[7];
  const float* att1 = (const float*)d_in[8];
  const float* b1   = (const float*)d_in[9];
  float* out = (float*)d_out;

  const int N  = in_sizes[0] / 256;
  const int E  = in_sizes[1] / 2;
  const int EA = E + N;

  // Workspace layout (floats):
  //   [0, N*512)            feat1 region; feat0 = first N*256 of it
  //   [N*512, N*512+N*128)  h buffer
  //   then alpha[EA*2], denom[N*2], mmax[N*2]
  float* ws    = (float*)d_ws;
  float* feat0 = ws;                       // N x 256
  float* feat1 = ws;                       // N x 512 (overlaps feat0; feat0 dead by then)
  float* hbuf  = ws + (size_t)N * 512;     // N x 128
  float* alpha = hbuf + (size_t)N * 128;   // EA*2
  float* denom = alpha + (size_t)EA * 2;   // N*2
  unsigned int* mmax = (unsigned int*)(denom + (size_t)N * 2);  // N*2

  const dim3 blk(256);
  const int tasks = EA * 2;
  const int gLogit = (tasks * 64 + 255) / 256;
  const int gEdge  = (tasks + 255) / 256;
  const int gScat0 = (int)(((long long)EA * 128 + 255) / 256);
  const int gScat1 = (int)(((long long)EA * 256 + 255) / 256);
  const int gRows  = (N + 63) / 64;

  // ---------------- Layer 0 ----------------
  hipMemsetAsync(mmax, 0, (size_t)N * 2 * 4, stream);
  hipMemsetAsync(denom, 0, (size_t)N * 2 * 4, stream);
  sgemm_dual<<<dim3(4, gRows), blk, 0, stream>>>(x, Wl0, Wr0, feat0, N, 256, 128);
  init_bias<<<(N * 128 + 255) / 256, blk, 0, stream>>>(hbuf, b0, N * 128, 127);
  edge_logit_max<64, 256><<<gLogit, blk, 0, stream>>>(ei, E, EA, feat0, att0, alpha, mmax);
  edge_expsum<<<gEdge, blk, 0, stream>>>(ei, E, EA, mmax, alpha, denom);
  alpha_norm<<<gEdge, blk, 0, stream>>>(ei, E, EA, denom, alpha);
  edge_scatter<64, 256, 7><<<gScat0, blk, 0, stream>>>(ei, E, EA, feat0, alpha, hbuf);
  relu_inplace<<<(N * 128 + 255) / 256, blk, 0, stream>>>(hbuf, N * 128);

  // ---------------- Layer 1 ----------------
  hipMemsetAsync(mmax, 0, (size_t)N * 2 * 4, stream);
  hipMemsetAsync(denom, 0, (size_t)N * 2 * 4, stream);
  sgemm_dual<<<dim3(8, gRows), blk, 0, stream>>>(hbuf, Wl1, Wr1, feat1, N, 128, 256);
  init_bias<<<(N * 256 + 255) / 256, blk, 0, stream>>>(out, b1, N * 256, 255);
  edge_logit_max<128, 512><<<gLogit, blk, 0, stream>>>(ei, E, EA, feat1, att1, alpha, mmax);
  edge_expsum<<<gEdge, blk, 0, stream>>>(ei, E, EA, mmax, alpha, denom);
  alpha_norm<<<gEdge, blk, 0, stream>>>(ei, E, EA, denom, alpha);
  edge_scatter<128, 512, 8><<<gScat1, blk, 0, stream>>>(ei, E, EA, feat1, alpha, out);
}

// Round 2
// 559.988 us; speedup vs baseline: 3.6282x; 3.6282x over previous
//
#include <hip/hip_runtime.h>
#include <cstdint>
#include <cstddef>

// GATv2 x2 layers. N=50000, E=800000, H=2, C_IN=256, C1=64, C2=128.
// Round 2: CSR build + fused per-node online-softmax gather (no atomics in
// aggregation), bias/relu folded into the fused epilogue.

#define NEG_SLOPE 0.2f

// ---------------------------------------------------------------------------
// C[M][2*NH] = A[M][K] @ [B1 | B2]  (B row-major [K][NH] each)
// 64x64 tile, BK=16, 4x4 per thread, 256 threads.
__global__ __launch_bounds__(256) void sgemm_dual(
    const float* __restrict__ A, const float* __restrict__ B1,
    const float* __restrict__ B2, float* __restrict__ C,
    int M, int K, int NH) {
  __shared__ float As[16][64];   // As[k][m]
  __shared__ float Bs[16][64];   // Bs[k][n]
  const int bn = blockIdx.x * 64;
  const int bm = blockIdx.y * 64;
  const float* __restrict__ B = (bn < NH) ? B1 : B2;
  const int bcol = (bn < NH) ? bn : (bn - NH);
  const int tid = threadIdx.x;
  const int tm = (tid >> 4) << 2;
  const int tn = (tid & 15) << 2;
  const int ar = tid >> 2;
  const int ac = (tid & 3) << 2;
  const int br = tid >> 4;
  const int bc = (tid & 15) << 2;
  const bool aok = (bm + ar) < M;
  float acc[4][4] = {};
  for (int k0 = 0; k0 < K; k0 += 16) {
    float4 av = make_float4(0.f, 0.f, 0.f, 0.f);
    if (aok) av = *(const float4*)&A[(size_t)(bm + ar) * K + k0 + ac];
    const float4 bv = *(const float4*)&B[(size_t)(k0 + br) * NH + bcol + bc];
    __syncthreads();
    As[ac + 0][ar] = av.x; As[ac + 1][ar] = av.y;
    As[ac + 2][ar] = av.z; As[ac + 3][ar] = av.w;
    *(float4*)&Bs[br][bc] = bv;
    __syncthreads();
#pragma unroll
    for (int k = 0; k < 16; ++k) {
      const float4 a = *(const float4*)&As[k][tm];
      const float4 b = *(const float4*)&Bs[k][tn];
      acc[0][0] += a.x * b.x; acc[0][1] += a.x * b.y; acc[0][2] += a.x * b.z; acc[0][3] += a.x * b.w;
      acc[1][0] += a.y * b.x; acc[1][1] += a.y * b.y; acc[1][2] += a.y * b.z; acc[1][3] += a.y * b.w;
      acc[2][0] += a.z * b.x; acc[2][1] += a.z * b.y; acc[2][2] += a.z * b.z; acc[2][3] += a.z * b.w;
      acc[3][0] += a.w * b.x; acc[3][1] += a.w * b.y; acc[3][2] += a.w * b.z; acc[3][3] += a.w * b.w;
    }
  }
  const int NT = 2 * NH;
#pragma unroll
  for (int i = 0; i < 4; ++i) {
    const int r = bm + tm + i;
    if (r < M) {
      float4 o = make_float4(acc[i][0], acc[i][1], acc[i][2], acc[i][3]);
      *(float4*)&C[(size_t)r * NT + bn + tn] = o;
    }
  }
}

// ---------------------------------------------------------------------------
// CSR build: count -> scan -> fill. Self-loops appended as (n -> n).
__global__ __launch_bounds__(256) void csr_count(
    const int* __restrict__ ei, int E, int EA, int* __restrict__ cnt) {
  const int i = blockIdx.x * blockDim.x + threadIdx.x;
  if (i >= EA) return;
  const int dst = (i < E) ? ei[E + i] : (i - E);
  atomicAdd(&cnt[dst], 1);
}

// per-256-block exclusive scan; writes block sums
__global__ __launch_bounds__(256) void scan_block(
    const int* __restrict__ cnt, int* __restrict__ excl,
    int* __restrict__ bsum, int n) {
  __shared__ int s[256];
  const int tid = threadIdx.x;
  const int i = blockIdx.x * 256 + tid;
  const int v = (i < n) ? cnt[i] : 0;
  s[tid] = v;
  __syncthreads();
  for (int off = 1; off < 256; off <<= 1) {
    const int t = (tid >= off) ? s[tid - off] : 0;
    __syncthreads();
    s[tid] += t;
    __syncthreads();
  }
  if (i < n) excl[i] = s[tid] - v;
  if (tid == 255) bsum[blockIdx.x] = s[255];
}

// single-block exclusive scan of block sums (nb <= 256)
__global__ __launch_bounds__(256) void scan_top(
    const int* __restrict__ bsum, int* __restrict__ bofs, int nb) {
  __shared__ int s[256];
  const int tid = threadIdx.x;
  const int v = (tid < nb) ? bsum[tid] : 0;
  s[tid] = v;
  __syncthreads();
  for (int off = 1; off < 256; off <<= 1) {
    const int t = (tid >= off) ? s[tid - off] : 0;
    __syncthreads();
    s[tid] += t;
    __syncthreads();
  }
  if (tid < nb) bofs[tid] = s[tid] - v;
}

__global__ __launch_bounds__(256) void scan_add(
    int* __restrict__ rowptr, const int* __restrict__ bofs, int n, int EA) {
  const int i = blockIdx.x * blockDim.x + threadIdx.x;
  if (i < n) rowptr[i] += bofs[i >> 8];
  if (i == 0) rowptr[n] = EA;
}

__global__ __launch_bounds__(256) void csr_fill(
    const int* __restrict__ ei, int E, int EA,
    const int* __restrict__ rowptr, int* __restrict__ wo,
    int* __restrict__ col) {
  const int i = blockIdx.x * blockDim.x + threadIdx.x;
  if (i >= EA) return;
  int src, dst;
  if (i < E) { src = ei[i]; dst = ei[E + i]; } else { src = dst = i - E; }
  const int pos = atomicAdd(&wo[dst], 1);
  col[rowptr[dst] + pos] = src;
}

// ---------------------------------------------------------------------------
// Fused per-node GATv2: logit + online softmax + aggregate + bias (+relu).
// One wave per node. Lanes 0-31: head 0, lanes 32-63: head 1.
// feat row layout [xl_h0|xl_h1|xr_h0|xr_h1], stride S = 4*C. V = C/32.
template <int C, int S, int V, bool RELU>
__global__ __launch_bounds__(256) void fused_gat(
    const int* __restrict__ rowptr, const int* __restrict__ col,
    const float* __restrict__ feat, const float* __restrict__ att,
    const float* __restrict__ bias, float* __restrict__ out, int N) {
  const int n = blockIdx.x * 4 + (threadIdx.x >> 6);
  if (n >= N) return;
  const int lane = threadIdx.x & 63;
  const int h = lane >> 5;
  const int co = h * C + (lane & 31) * V;   // offset within a 2C half-row

  float xr[V], at[V], O[V];
  {
    const float* __restrict__ pr = feat + (size_t)n * S + 2 * C + co;
#pragma unroll
    for (int j = 0; j < V; ++j) { xr[j] = pr[j]; at[j] = att[co + j]; O[j] = 0.f; }
  }
  float m = -INFINITY, l = 0.f;
  const int e0 = rowptr[n], e1 = rowptr[n + 1];

  float xl[V];
  {
    const float* __restrict__ p = feat + (size_t)col[e0] * S + co;
    if constexpr (V == 4) {
      const float4 t = *(const float4*)p; xl[0] = t.x; xl[1] = t.y; xl[2] = t.z; xl[3] = t.w;
    } else {
      const float2 t = *(const float2*)p; xl[0] = t.x; xl[1] = t.y;
    }
  }
  for (int e = e0; e < e1; ++e) {
    float cur[V];
#pragma unroll
    for (int j = 0; j < V; ++j) cur[j] = xl[j];
    if (e + 1 < e1) {
      const float* __restrict__ p = feat + (size_t)col[e + 1] * S + co;
      if constexpr (V == 4) {
        const float4 t = *(const float4*)p; xl[0] = t.x; xl[1] = t.y; xl[2] = t.z; xl[3] = t.w;
      } else {
        const float2 t = *(const float2*)p; xl[0] = t.x; xl[1] = t.y;
      }
    }
    float pacc = 0.f;
#pragma unroll
    for (int j = 0; j < V; ++j) {
      float sv = cur[j] + xr[j];
      sv = (sv > 0.f) ? sv : NEG_SLOPE * sv;
      pacc += sv * at[j];
    }
    // butterfly reduce within each 32-lane head group
#pragma unroll
    for (int off = 16; off; off >>= 1) pacc += __shfl_xor(pacc, off, 64);
    const float mn = fmaxf(m, pacc);
    const float scale = __expf(m - mn);
    const float w = __expf(pacc - mn);
    l = l * scale + w;
#pragma unroll
    for (int j = 0; j < V; ++j) O[j] = O[j] * scale + w * cur[j];
    m = mn;
  }
  const float inv = 1.f / l;
  float* __restrict__ po = out + (size_t)n * (2 * C) + co;
#pragma unroll
  for (int j = 0; j < V; ++j) {
    float v = O[j] * inv + bias[co + j];
    if constexpr (RELU) v = fmaxf(v, 0.f);
    po[j] = v;
  }
}

// ---------------------------------------------------------------------------
extern "C" void kernel_launch(void* const* d_in, const int* in_sizes, int n_in,
                              void* d_out, int out_size, void* d_ws, size_t ws_size,
                              hipStream_t stream) {
  const float* x    = (const float*)d_in[0];
  const int*   ei   = (const int*)d_in[1];
  const float* Wl0  = (const float*)d_in[2];
  const float* Wr0  = (const float*)d_in[3];
  const float* att0 = (const float*)d_in[4];
  const float* b0   = (const float*)d_in[5];
  const float* Wl1  = (const float*)d_in[6];
  const float* Wr1  = (const float*)d_in[7];
  const float* att1 = (const float*)d_in[8];
  const float* b1   = (const float*)d_in[9];
  float* out = (float*)d_out;

  const int N  = in_sizes[0] / 256;
  const int E  = in_sizes[1] / 2;
  const int EA = E + N;

  // Workspace layout:
  //   feat1: N*512 f (feat0 = first N*256 of it)
  //   hbuf : N*128 f
  //   ints : rowptr[N+1], cnt[N], wo[N], bsum[256], bofs[256], col[EA]
  float* ws    = (float*)d_ws;
  float* feat0 = ws;
  float* feat1 = ws;
  float* hbuf  = ws + (size_t)N * 512;
  int* rowptr = (int*)(hbuf + (size_t)N * 128);
  int* cnt    = rowptr + (N + 1);
  int* wo     = cnt + N;
  int* bsum   = wo + N;
  int* bofs   = bsum + 256;
  int* col    = bofs + 256;

  const dim3 blk(256);
  const int gEA   = (EA + 255) / 256;
  const int gScan = (N + 255) / 256;   // 196 <= 256
  const int gRows = (N + 63) / 64;
  const int gNode = (N + 3) / 4;

  // ---- CSR build (shared by both layers) ----
  hipMemsetAsync(cnt, 0, (size_t)N * 4, stream);
  hipMemsetAsync(wo, 0, (size_t)N * 4, stream);
  csr_count<<<gEA, blk, 0, stream>>>(ei, E, EA, cnt);
  scan_block<<<gScan, blk, 0, stream>>>(cnt, rowptr, bsum, N);
  scan_top<<<1, blk, 0, stream>>>(bsum, bofs, gScan);
  scan_add<<<gScan, blk, 0, stream>>>(rowptr, bofs, N, EA);
  csr_fill<<<gEA, blk, 0, stream>>>(ei, E, EA, rowptr, wo, col);

  // ---- Layer 0 ----
  sgemm_dual<<<dim3(4, gRows), blk, 0, stream>>>(x, Wl0, Wr0, feat0, N, 256, 128);
  fused_gat<64, 256, 2, true><<<gNode, blk, 0, stream>>>(
      rowptr, col, feat0, att0, b0, hbuf, N);

  // ---- Layer 1 ----
  sgemm_dual<<<dim3(8, gRows), blk, 0, stream>>>(hbuf, Wl1, Wr1, feat1, N, 128, 256);
  fused_gat<128, 512, 4, false><<<gNode, blk, 0, stream>>>(
      rowptr, col, feat1, att1, b1, out, N);
}

// Round 3
// 392.807 us; speedup vs baseline: 5.1723x; 1.4256x over previous
//
#include <hip/hip_runtime.h>
#include <cstdint>
#include <cstddef>

// GATv2 x2. Round 3: f16 MFMA GEMMs + fp16 gather buffers.
// N=50000, E=800000, H=2, C_IN=256, C1=64, C2=128.

#define NEG_SLOPE 0.2f

typedef _Float16 f16x8 __attribute__((ext_vector_type(8)));
typedef _Float16 f16x4 __attribute__((ext_vector_type(4)));
typedef float f32x4 __attribute__((ext_vector_type(4)));

// ---------------------------------------------------------------------------
// cast fp32 -> fp16, 4 elems/thread
__global__ __launch_bounds__(256) void cast_f2h(
    const float* __restrict__ src, _Float16* __restrict__ dst, int total4) {
  const int t = blockIdx.x * blockDim.x + threadIdx.x;
  if (t >= total4) return;
  const float4 v = *(const float4*)&src[(size_t)t * 4];
  f16x4 h;
  h[0] = (_Float16)v.x; h[1] = (_Float16)v.y; h[2] = (_Float16)v.z; h[3] = (_Float16)v.w;
  *(f16x4*)&dst[(size_t)t * 4] = h;
}

// Bt[n][k] = (n<NH ? Wl[k][n] : Wr[k][n-NH]), fp16
__global__ __launch_bounds__(256) void tcast_w(
    const float* __restrict__ Wl, const float* __restrict__ Wr,
    _Float16* __restrict__ Bt, int K, int NH) {
  const int t = blockIdx.x * blockDim.x + threadIdx.x;
  if (t >= 2 * NH * K) return;
  const int n = t / K, k = t - n * K;
  const float v = (n < NH) ? Wl[(size_t)k * NH + n] : Wr[(size_t)k * NH + (n - NH)];
  Bt[t] = (_Float16)v;
}

// ---------------------------------------------------------------------------
// C[M][NT](f16) = A[M][K](f16) @ Bt[NT][K]^T, MFMA f16.
// 128x64 tile, BK=32, 256 threads (4 waves), wave computes 64x32.
__global__ __launch_bounds__(256) void hgemm_tn(
    const _Float16* __restrict__ A, const _Float16* __restrict__ Bt,
    _Float16* __restrict__ C, int M, int NT, int K) {
  constexpr int LDA = 40;                       // padded row stride (halves)
  __shared__ _Float16 As[128 * LDA];
  __shared__ _Float16 Bs[64 * LDA];
  const int bm = blockIdx.y * 128;
  const int bn = blockIdx.x * 64;
  const int tid = threadIdx.x;
  const int lane = tid & 63;
  const int wave = tid >> 6;
  const int wr = (wave >> 1) * 64;              // wave row offset in tile
  const int wc = (wave & 1) * 32;               // wave col offset
  const int sr = tid >> 2;                      // staging row 0..63
  const int ss = (tid & 3) * 8;                 // staging k-slot (halves)
  const int l15 = lane & 15;
  const int kq = (lane >> 4) * 8;               // fragment k-offset
  f32x4 acc[4][2] = {};
  for (int k0 = 0; k0 < K; k0 += 32) {
    f16x8 a0 = {}, a1 = {};
    const int r0 = bm + sr, r1 = r0 + 64;
    if (r0 < M) a0 = *(const f16x8*)&A[(size_t)r0 * K + k0 + ss];
    if (r1 < M) a1 = *(const f16x8*)&A[(size_t)r1 * K + k0 + ss];
    const f16x8 b0 = *(const f16x8*)&Bt[(size_t)(bn + sr) * K + k0 + ss];
    __syncthreads();
    *(f16x8*)&As[sr * LDA + ss] = a0;
    *(f16x8*)&As[(sr + 64) * LDA + ss] = a1;
    *(f16x8*)&Bs[sr * LDA + ss] = b0;
    __syncthreads();
    f16x8 bf[2];
#pragma unroll
    for (int ni = 0; ni < 2; ++ni)
      bf[ni] = *(const f16x8*)&Bs[(wc + ni * 16 + l15) * LDA + kq];
#pragma unroll
    for (int mi = 0; mi < 4; ++mi) {
      const f16x8 af = *(const f16x8*)&As[(wr + mi * 16 + l15) * LDA + kq];
#pragma unroll
      for (int ni = 0; ni < 2; ++ni)
        acc[mi][ni] = __builtin_amdgcn_mfma_f32_16x16x32_f16(af, bf[ni], acc[mi][ni], 0, 0, 0);
    }
  }
  // C/D: col = lane&15, row = (lane>>4)*4 + reg  [m89/m91-verified]
  const int crow0 = (lane >> 4) * 4;
#pragma unroll
  for (int mi = 0; mi < 4; ++mi) {
#pragma unroll
    for (int r = 0; r < 4; ++r) {
      const int row = bm + wr + mi * 16 + crow0 + r;
      if (row < M) {
#pragma unroll
        for (int ni = 0; ni < 2; ++ni)
          C[(size_t)row * NT + bn + wc + ni * 16 + l15] = (_Float16)acc[mi][ni][r];
      }
    }
  }
}

// ---------------------------------------------------------------------------
// CSR build (self-loops appended as (n->n)).
__global__ __launch_bounds__(256) void csr_count(
    const int* __restrict__ ei, int E, int EA, int* __restrict__ cnt) {
  const int i = blockIdx.x * blockDim.x + threadIdx.x;
  if (i >= EA) return;
  const int dst = (i < E) ? ei[E + i] : (i - E);
  atomicAdd(&cnt[dst], 1);
}

__global__ __launch_bounds__(256) void scan_block(
    const int* __restrict__ cnt, int* __restrict__ excl,
    int* __restrict__ bsum, int n) {
  __shared__ int s[256];
  const int tid = threadIdx.x;
  const int i = blockIdx.x * 256 + tid;
  const int v = (i < n) ? cnt[i] : 0;
  s[tid] = v;
  __syncthreads();
  for (int off = 1; off < 256; off <<= 1) {
    const int t = (tid >= off) ? s[tid - off] : 0;
    __syncthreads();
    s[tid] += t;
    __syncthreads();
  }
  if (i < n) excl[i] = s[tid] - v;
  if (tid == 255) bsum[blockIdx.x] = s[255];
}

__global__ __launch_bounds__(256) void scan_top(
    const int* __restrict__ bsum, int* __restrict__ bofs, int nb) {
  __shared__ int s[256];
  const int tid = threadIdx.x;
  const int v = (tid < nb) ? bsum[tid] : 0;
  s[tid] = v;
  __syncthreads();
  for (int off = 1; off < 256; off <<= 1) {
    const int t = (tid >= off) ? s[tid - off] : 0;
    __syncthreads();
    s[tid] += t;
    __syncthreads();
  }
  if (tid < nb) bofs[tid] = s[tid] - v;
}

__global__ __launch_bounds__(256) void scan_add(
    int* __restrict__ rowptr, const int* __restrict__ bofs, int n, int EA) {
  const int i = blockIdx.x * blockDim.x + threadIdx.x;
  if (i < n) rowptr[i] += bofs[i >> 8];
  if (i == 0) rowptr[n] = EA;
}

__global__ __launch_bounds__(256) void csr_fill(
    const int* __restrict__ ei, int E, int EA,
    const int* __restrict__ rowptr, int* __restrict__ wo,
    int* __restrict__ col) {
  const int i = blockIdx.x * blockDim.x + threadIdx.x;
  if (i >= EA) return;
  int src, dst;
  if (i < E) { src = ei[i]; dst = ei[E + i]; } else { src = dst = i - E; }
  const int pos = atomicAdd(&wo[dst], 1);
  col[rowptr[dst] + pos] = src;
}

// ---------------------------------------------------------------------------
// Fused per-node GATv2 on fp16 features: logit + online softmax + aggregate
// + bias (+relu). One wave per node; lanes 0-31 head0, 32-63 head1.
// feat row [xl_h0|xl_h1|xr_h0|xr_h1], stride S halves. V = C/32.
template <int C, int S, int V, bool RELU, bool OUT16>
__global__ __launch_bounds__(256) void fused_gat_h(
    const int* __restrict__ rowptr, const int* __restrict__ col,
    const _Float16* __restrict__ feat, const float* __restrict__ att,
    const float* __restrict__ bias, _Float16* __restrict__ out16,
    float* __restrict__ out32, int N) {
  typedef _Float16 hv_t __attribute__((ext_vector_type(V)));
  const int n = blockIdx.x * 4 + (threadIdx.x >> 6);
  if (n >= N) return;
  const int lane = threadIdx.x & 63;
  const int h = lane >> 5;
  const int co = h * C + (lane & 31) * V;

  float xr[V], at[V], O[V];
  {
    const hv_t pr = *(const hv_t*)&feat[(size_t)n * S + 2 * C + co];
#pragma unroll
    for (int j = 0; j < V; ++j) { xr[j] = (float)pr[j]; at[j] = att[co + j]; O[j] = 0.f; }
  }
  float m = -INFINITY, l = 0.f;
  const int e0 = rowptr[n], e1 = rowptr[n + 1];

  hv_t xl = *(const hv_t*)&feat[(size_t)col[e0] * S + co];
  for (int e = e0; e < e1; ++e) {
    float cur[V];
#pragma unroll
    for (int j = 0; j < V; ++j) cur[j] = (float)xl[j];
    if (e + 1 < e1) xl = *(const hv_t*)&feat[(size_t)col[e + 1] * S + co];
    float pacc = 0.f;
#pragma unroll
    for (int j = 0; j < V; ++j) {
      float sv = cur[j] + xr[j];
      sv = (sv > 0.f) ? sv : NEG_SLOPE * sv;
      pacc += sv * at[j];
    }
#pragma unroll
    for (int off = 16; off; off >>= 1) pacc += __shfl_xor(pacc, off, 64);
    const float mn = fmaxf(m, pacc);
    const float scale = __expf(m - mn);
    const float w = __expf(pacc - mn);
    l = l * scale + w;
#pragma unroll
    for (int j = 0; j < V; ++j) O[j] = O[j] * scale + w * cur[j];
    m = mn;
  }
  const float inv = 1.f / l;
  if constexpr (OUT16) {
    hv_t o;
#pragma unroll
    for (int j = 0; j < V; ++j) {
      float v = O[j] * inv + bias[co + j];
      if constexpr (RELU) v = fmaxf(v, 0.f);
      o[j] = (_Float16)v;
    }
    *(hv_t*)&out16[(size_t)n * (2 * C) + co] = o;
  } else {
#pragma unroll
    for (int j = 0; j < V; ++j) {
      float v = O[j] * inv + bias[co + j];
      if constexpr (RELU) v = fmaxf(v, 0.f);
      out32[(size_t)n * (2 * C) + co + j] = v;
    }
  }
}

// ---------------------------------------------------------------------------
extern "C" void kernel_launch(void* const* d_in, const int* in_sizes, int n_in,
                              void* d_out, int out_size, void* d_ws, size_t ws_size,
                              hipStream_t stream) {
  const float* x    = (const float*)d_in[0];
  const int*   ei   = (const int*)d_in[1];
  const float* Wl0  = (const float*)d_in[2];
  const float* Wr0  = (const float*)d_in[3];
  const float* att0 = (const float*)d_in[4];
  const float* b0   = (const float*)d_in[5];
  const float* Wl1  = (const float*)d_in[6];
  const float* Wr1  = (const float*)d_in[7];
  const float* att1 = (const float*)d_in[8];
  const float* b1   = (const float*)d_in[9];
  float* out = (float*)d_out;

  const int N  = in_sizes[0] / 256;
  const int E  = in_sizes[1] / 2;
  const int EA = E + N;

  // Workspace (halves):
  //   feat:  [0, N*512)        feat1h (L1); feat0h = first N*256 of it
  //   ha:    [N*512, N*640)    L0 output, fp16 (only feeds GEMM1)
  //   xa:    [N*640, N*896)    x cast to fp16
  //   Bt0:   [N*896, +65536)   W0^T fp16 [256][256]
  //   Bt1:   [.., +65536)      W1^T fp16 [512][128]
  //   then ints: rowptr[N+1], cnt[N], wo[N], bsum[256], bofs[256], col[EA]
  _Float16* hw    = (_Float16*)d_ws;
  _Float16* feat0 = hw;
  _Float16* feat1 = hw;
  _Float16* ha    = hw + (size_t)N * 512;
  _Float16* xa    = hw + (size_t)N * 640;
  _Float16* Bt0   = hw + (size_t)N * 896;
  _Float16* Bt1   = Bt0 + 65536;
  int* rowptr = (int*)(Bt1 + 65536);
  int* cnt    = rowptr + (N + 1);
  int* wo     = cnt + N;
  int* bsum   = wo + N;
  int* bofs   = bsum + 256;
  int* col    = bofs + 256;

  const dim3 blk(256);
  const int gEA   = (EA + 255) / 256;
  const int gScan = (N + 255) / 256;
  const int gM    = (N + 127) / 128;
  const int gNode = (N + 3) / 4;

  // casts
  cast_f2h<<<(N * 256 / 4 + 255) / 256, blk, 0, stream>>>(x, xa, N * 64);
  tcast_w<<<(65536 + 255) / 256, blk, 0, stream>>>(Wl0, Wr0, Bt0, 256, 128);
  tcast_w<<<(65536 + 255) / 256, blk, 0, stream>>>(Wl1, Wr1, Bt1, 128, 256);

  // CSR build
  hipMemsetAsync(cnt, 0, (size_t)N * 4, stream);
  hipMemsetAsync(wo, 0, (size_t)N * 4, stream);
  csr_count<<<gEA, blk, 0, stream>>>(ei, E, EA, cnt);
  scan_block<<<gScan, blk, 0, stream>>>(cnt, rowptr, bsum, N);
  scan_top<<<1, blk, 0, stream>>>(bsum, bofs, gScan);
  scan_add<<<gScan, blk, 0, stream>>>(rowptr, bofs, N, EA);
  csr_fill<<<gEA, blk, 0, stream>>>(ei, E, EA, rowptr, wo, col);

  // Layer 0
  hgemm_tn<<<dim3(4, gM), blk, 0, stream>>>(xa, Bt0, feat0, N, 256, 256);
  fused_gat_h<64, 256, 2, true, true><<<gNode, blk, 0, stream>>>(
      rowptr, col, feat0, att0, b0, ha, nullptr, N);

  // Layer 1
  hgemm_tn<<<dim3(8, gM), blk, 0, stream>>>(ha, Bt1, feat1, N, 512, 128);
  fused_gat_h<128, 512, 4, false, false><<<gNode, blk, 0, stream>>>(
      rowptr, col, feat1, att1, b1, nullptr, out, N);
}

// Round 4
// 298.360 us; speedup vs baseline: 6.8097x; 1.3166x over previous
//
#include <hip/hip_runtime.h>
#include <cstdint>
#include <cstddef>

// GATv2 x2. Round 4: packed-f16 + fdot2 logit, DPP reduce, defer-max,
// 2-deep prefetch in fused gather; BK=64 MFMA GEMM.
// N=50000, E=800000, H=2, C_IN=256, C1=64, C2=128.

#define NEG_SLOPE 0.2f

typedef _Float16 f16x8 __attribute__((ext_vector_type(8)));
typedef _Float16 f16x4 __attribute__((ext_vector_type(4)));
typedef _Float16 f16x2 __attribute__((ext_vector_type(2)));
typedef float f32x4 __attribute__((ext_vector_type(4)));

// DPP-assisted add: x += dpp_perm(x). ctrl: 0xB1=xor1, 0x4E=xor2,
// 0x124=row_ror:4, 0x128=row_ror:8 (rotations are fine for reductions).
#define DPPADD(x, CTRL)                                                        \
  do {                                                                         \
    int _y = __builtin_amdgcn_update_dpp(0, __float_as_int(x), CTRL, 0xf, 0xf, \
                                         true);                                \
    x += __int_as_float(_y);                                                   \
  } while (0)

// ---------------------------------------------------------------------------
__global__ __launch_bounds__(256) void cast_f2h(
    const float* __restrict__ src, _Float16* __restrict__ dst, int total4) {
  const int t = blockIdx.x * blockDim.x + threadIdx.x;
  if (t >= total4) return;
  const float4 v = *(const float4*)&src[(size_t)t * 4];
  f16x4 h;
  h[0] = (_Float16)v.x; h[1] = (_Float16)v.y; h[2] = (_Float16)v.z; h[3] = (_Float16)v.w;
  *(f16x4*)&dst[(size_t)t * 4] = h;
}

// Bt[n][k] = (n<NH ? Wl[k][n] : Wr[k][n-NH]), fp16
__global__ __launch_bounds__(256) void tcast_w(
    const float* __restrict__ Wl, const float* __restrict__ Wr,
    _Float16* __restrict__ Bt, int K, int NH) {
  const int t = blockIdx.x * blockDim.x + threadIdx.x;
  if (t >= 2 * NH * K) return;
  const int n = t / K, k = t - n * K;
  const float v = (n < NH) ? Wl[(size_t)k * NH + n] : Wr[(size_t)k * NH + (n - NH)];
  Bt[t] = (_Float16)v;
}

// ---------------------------------------------------------------------------
// C[M][NT](f16) = A[M][K](f16) @ Bt[NT][K]^T. 128x64 tile, BK=64, 4 waves.
__global__ __launch_bounds__(256) void hgemm_tn(
    const _Float16* __restrict__ A, const _Float16* __restrict__ Bt,
    _Float16* __restrict__ C, int M, int NT, int K) {
  constexpr int LDA = 88;  // halves; 176B row stride = 11*16 (aligned, ~2-way banks)
  __shared__ _Float16 As[128 * LDA];
  __shared__ _Float16 Bs[64 * LDA];
  const int bm = blockIdx.y * 128;
  const int bn = blockIdx.x * 64;
  const int tid = threadIdx.x;
  const int lane = tid & 63;
  const int wave = tid >> 6;
  const int wr = (wave >> 1) * 64;
  const int wc = (wave & 1) * 32;
  const int l15 = lane & 15;
  const int kq = (lane >> 4) * 8;
  f32x4 acc[4][2] = {};
  for (int k0 = 0; k0 < K; k0 += 64) {
    f16x8 a[4], b[2];
#pragma unroll
    for (int i = 0; i < 4; ++i) {
      const int c = tid + 256 * i;
      const int r = c >> 3, ks = (c & 7) * 8;
      const int row = bm + r;
      a[i] = (row < M) ? *(const f16x8*)&A[(size_t)row * K + k0 + ks] : f16x8{};
    }
#pragma unroll
    for (int i = 0; i < 2; ++i) {
      const int c = tid + 256 * i;
      const int r = c >> 3, ks = (c & 7) * 8;
      b[i] = *(const f16x8*)&Bt[(size_t)(bn + r) * K + k0 + ks];
    }
    __syncthreads();
#pragma unroll
    for (int i = 0; i < 4; ++i) {
      const int c = tid + 256 * i;
      const int r = c >> 3, ks = (c & 7) * 8;
      *(f16x8*)&As[r * LDA + ks] = a[i];
    }
#pragma unroll
    for (int i = 0; i < 2; ++i) {
      const int c = tid + 256 * i;
      const int r = c >> 3, ks = (c & 7) * 8;
      *(f16x8*)&Bs[r * LDA + ks] = b[i];
    }
    __syncthreads();
#pragma unroll
    for (int kk = 0; kk < 64; kk += 32) {
      f16x8 bf[2];
#pragma unroll
      for (int ni = 0; ni < 2; ++ni)
        bf[ni] = *(const f16x8*)&Bs[(wc + ni * 16 + l15) * LDA + kk + kq];
#pragma unroll
      for (int mi = 0; mi < 4; ++mi) {
        const f16x8 af = *(const f16x8*)&As[(wr + mi * 16 + l15) * LDA + kk + kq];
#pragma unroll
        for (int ni = 0; ni < 2; ++ni)
          acc[mi][ni] = __builtin_amdgcn_mfma_f32_16x16x32_f16(af, bf[ni], acc[mi][ni], 0, 0, 0);
      }
    }
  }
  const int crow0 = (lane >> 4) * 4;
#pragma unroll
  for (int mi = 0; mi < 4; ++mi) {
#pragma unroll
    for (int r = 0; r < 4; ++r) {
      const int row = bm + wr + mi * 16 + crow0 + r;
      if (row < M) {
#pragma unroll
        for (int ni = 0; ni < 2; ++ni)
          C[(size_t)row * NT + bn + wc + ni * 16 + l15] = (_Float16)acc[mi][ni][r];
      }
    }
  }
}

// ---------------------------------------------------------------------------
// CSR build (self-loops appended as (n->n)).
__global__ __launch_bounds__(256) void csr_count(
    const int* __restrict__ ei, int E, int EA, int* __restrict__ cnt) {
  const int i = blockIdx.x * blockDim.x + threadIdx.x;
  if (i >= EA) return;
  const int dst = (i < E) ? ei[E + i] : (i - E);
  atomicAdd(&cnt[dst], 1);
}

__global__ __launch_bounds__(256) void scan_block(
    const int* __restrict__ cnt, int* __restrict__ excl,
    int* __restrict__ bsum, int n) {
  __shared__ int s[256];
  const int tid = threadIdx.x;
  const int i = blockIdx.x * 256 + tid;
  const int v = (i < n) ? cnt[i] : 0;
  s[tid] = v;
  __syncthreads();
  for (int off = 1; off < 256; off <<= 1) {
    const int t = (tid >= off) ? s[tid - off] : 0;
    __syncthreads();
    s[tid] += t;
    __syncthreads();
  }
  if (i < n) excl[i] = s[tid] - v;
  if (tid == 255) bsum[blockIdx.x] = s[255];
}

__global__ __launch_bounds__(256) void scan_top(
    const int* __restrict__ bsum, int* __restrict__ bofs, int nb) {
  __shared__ int s[256];
  const int tid = threadIdx.x;
  const int v = (tid < nb) ? bsum[tid] : 0;
  s[tid] = v;
  __syncthreads();
  for (int off = 1; off < 256; off <<= 1) {
    const int t = (tid >= off) ? s[tid - off] : 0;
    __syncthreads();
    s[tid] += t;
    __syncthreads();
  }
  if (tid < nb) bofs[tid] = s[tid] - v;
}

__global__ __launch_bounds__(256) void scan_add(
    int* __restrict__ rowptr, const int* __restrict__ bofs, int n, int EA) {
  const int i = blockIdx.x * blockDim.x + threadIdx.x;
  if (i < n) rowptr[i] += bofs[i >> 8];
  if (i == 0) rowptr[n] = EA;
}

__global__ __launch_bounds__(256) void csr_fill(
    const int* __restrict__ ei, int E, int EA,
    const int* __restrict__ rowptr, int* __restrict__ wo,
    int* __restrict__ col) {
  const int i = blockIdx.x * blockDim.x + threadIdx.x;
  if (i >= EA) return;
  int src, dst;
  if (i < E) { src = ei[i]; dst = ei[E + i]; } else { src = dst = i - E; }
  const int pos = atomicAdd(&wo[dst], 1);
  col[rowptr[dst] + pos] = src;
}

// ---------------------------------------------------------------------------
// Fused per-node GATv2 (fp16 features). One wave per node; lanes 0-31 head0,
// 32-63 head1; V = C/32 channels per lane. feat row [xl_h0|xl_h1|xr_h0|xr_h1],
// stride 2^LOGS halves (power of two -> shift addressing).
template <int C, int LOGS, int V, bool RELU, bool OUT16>
__global__ __launch_bounds__(256) void fused_gat_h(
    const int* __restrict__ rowptr, const int* __restrict__ col,
    const _Float16* __restrict__ feat, const float* __restrict__ att,
    const float* __restrict__ bias, _Float16* __restrict__ out16,
    float* __restrict__ out32, int N) {
  constexpr int P = V / 2;
  typedef _Float16 hv __attribute__((ext_vector_type(V)));
  const int n = blockIdx.x * 4 + (threadIdx.x >> 6);
  if (n >= N) return;
  const int lane = threadIdx.x & 63;
  const int h = lane >> 5;
  const int co = h * C + (lane & 31) * V;

  f16x2 xr[P], at[P];
  float O[V];
  {
    const int base = (n << LOGS) + 2 * C + co;
#pragma unroll
    for (int p = 0; p < P; ++p) xr[p] = *(const f16x2*)&feat[base + 2 * p];
#pragma unroll
    for (int p = 0; p < P; ++p)
      at[p] = f16x2{(_Float16)att[co + 2 * p], (_Float16)att[co + 2 * p + 1]};
#pragma unroll
    for (int j = 0; j < V; ++j) O[j] = 0.f;
  }
  float m = -INFINITY, l = 0.f;
  const int e0 = rowptr[n], e1 = rowptr[n + 1];

  const f16x2 z2 = f16x2{(_Float16)0.f, (_Float16)0.f};
  const f16x2 ns2 = f16x2{(_Float16)NEG_SLOPE, (_Float16)NEG_SLOPE};

  const int cA0 = col[e0];
  hv cur = *(const hv*)&feat[(cA0 << LOGS) + co];
  int cNx = (e0 + 1 < e1) ? col[e0 + 1] : cA0;
  for (int e = e0; e < e1; ++e) {
    const hv nxt = *(const hv*)&feat[(cNx << LOGS) + co];  // prefetch xl[e+1]
    const int cFu = (e + 2 < e1) ? col[e + 2] : cA0;       // prefetch col[e+2]
    // logit = att . leaky_relu(cur + xr), packed f16 + fdot2
    float pacc = 0.f;
#pragma unroll
    for (int p = 0; p < P; ++p) {
      const f16x2 c2 = f16x2{cur[2 * p], cur[2 * p + 1]};
      const f16x2 s = c2 + xr[p];
      const f16x2 mx = __builtin_elementwise_max(s, z2);
      const f16x2 mn = __builtin_elementwise_min(s, z2);
      const f16x2 lk = mn * ns2 + mx;
      pacc = __builtin_amdgcn_fdot2(lk, at[p], pacc, false);
    }
    // reduce over the head's 32 lanes: 4 DPP steps + one 16-crossing shuffle
    DPPADD(pacc, 0xB1);   // quad_perm xor1
    DPPADD(pacc, 0x4E);   // quad_perm xor2
    DPPADD(pacc, 0x124);  // row_ror:4
    DPPADD(pacc, 0x128);  // row_ror:8
    pacc += __shfl_xor(pacc, 16, 64);
    // online softmax with defer-max (THR=8): exact, bounds w by e^8
    if (__any(pacc - m > 8.f)) {
      const float mn2 = fmaxf(m, pacc);
      const float scale = __expf(m - mn2);
      const float w = __expf(pacc - mn2);
      l = l * scale + w;
#pragma unroll
      for (int j = 0; j < V; ++j) O[j] = O[j] * scale + w * (float)cur[j];
      m = mn2;
    } else {
      const float w = __expf(pacc - m);
      l += w;
#pragma unroll
      for (int j = 0; j < V; ++j) O[j] += w * (float)cur[j];
    }
    cur = nxt;
    cNx = cFu;
  }
  const float inv = 1.f / l;
  if constexpr (OUT16) {
    typedef _Float16 ov __attribute__((ext_vector_type(V)));
    ov o;
#pragma unroll
    for (int j = 0; j < V; ++j) {
      float v = O[j] * inv + bias[co + j];
      if constexpr (RELU) v = fmaxf(v, 0.f);
      o[j] = (_Float16)v;
    }
    *(ov*)&out16[n * (2 * C) + co] = o;
  } else {
    float4 o;
    o.x = O[0] * inv + bias[co + 0];
    o.y = O[1] * inv + bias[co + 1];
    o.z = O[2] * inv + bias[co + 2];
    o.w = O[3] * inv + bias[co + 3];
    *(float4*)&out32[(size_t)n * (2 * C) + co] = o;
  }
}

// ---------------------------------------------------------------------------
extern "C" void kernel_launch(void* const* d_in, const int* in_sizes, int n_in,
                              void* d_out, int out_size, void* d_ws, size_t ws_size,
                              hipStream_t stream) {
  const float* x    = (const float*)d_in[0];
  const int*   ei   = (const int*)d_in[1];
  const float* Wl0  = (const float*)d_in[2];
  const float* Wr0  = (const float*)d_in[3];
  const float* att0 = (const float*)d_in[4];
  const float* b0   = (const float*)d_in[5];
  const float* Wl1  = (const float*)d_in[6];
  const float* Wr1  = (const float*)d_in[7];
  const float* att1 = (const float*)d_in[8];
  const float* b1   = (const float*)d_in[9];
  float* out = (float*)d_out;

  const int N  = in_sizes[0] / 256;
  const int E  = in_sizes[1] / 2;
  const int EA = E + N;

  _Float16* hw    = (_Float16*)d_ws;
  _Float16* feat0 = hw;                        // N x 256 (overlapped by feat1)
  _Float16* feat1 = hw;                        // N x 512
  _Float16* ha    = hw + (size_t)N * 512;      // N x 128 (L0 out, f16)
  _Float16* xa    = hw + (size_t)N * 640;      // N x 256 (x in f16)
  _Float16* Bt0   = hw + (size_t)N * 896;      // 256 x 256
  _Float16* Bt1   = Bt0 + 65536;               // 512 x 128
  int* rowptr = (int*)(Bt1 + 65536);
  int* cnt    = rowptr + (N + 1);
  int* wo     = cnt + N;
  int* bsum   = wo + N;
  int* bofs   = bsum + 256;
  int* col    = bofs + 256;

  const dim3 blk(256);
  const int gEA   = (EA + 255) / 256;
  const int gScan = (N + 255) / 256;
  const int gM    = (N + 127) / 128;
  const int gNode = (N + 3) / 4;

  cast_f2h<<<(N * 64 + 255) / 256, blk, 0, stream>>>(x, xa, N * 64);
  tcast_w<<<(65536 + 255) / 256, blk, 0, stream>>>(Wl0, Wr0, Bt0, 256, 128);
  tcast_w<<<(65536 + 255) / 256, blk, 0, stream>>>(Wl1, Wr1, Bt1, 128, 256);

  hipMemsetAsync(cnt, 0, (size_t)N * 4, stream);
  hipMemsetAsync(wo, 0, (size_t)N * 4, stream);
  csr_count<<<gEA, blk, 0, stream>>>(ei, E, EA, cnt);
  scan_block<<<gScan, blk, 0, stream>>>(cnt, rowptr, bsum, N);
  scan_top<<<1, blk, 0, stream>>>(bsum, bofs, gScan);
  scan_add<<<gScan, blk, 0, stream>>>(rowptr, bofs, N, EA);
  csr_fill<<<gEA, blk, 0, stream>>>(ei, E, EA, rowptr, wo, col);

  // Layer 0
  hgemm_tn<<<dim3(4, gM), blk, 0, stream>>>(xa, Bt0, feat0, N, 256, 256);
  fused_gat_h<64, 8, 2, true, true><<<gNode, blk, 0, stream>>>(
      rowptr, col, feat0, att0, b0, ha, nullptr, N);

  // Layer 1
  hgemm_tn<<<dim3(8, gM), blk, 0, stream>>>(ha, Bt1, feat1, N, 512, 128);
  fused_gat_h<128, 9, 4, false, false><<<gNode, blk, 0, stream>>>(
      rowptr, col, feat1, att1, b1, nullptr, out, N);
}

// Round 5
// 293.348 us; speedup vs baseline: 6.9260x; 1.0171x over previous
//
#include <hip/hip_runtime.h>
#include <cstdint>
#include <cstddef>

// GATv2 x2. Round 5: 4-edges-per-wave subgroup fused gather (16 lanes/edge,
// all channels across 16 lanes, 3-DPP head-half reduce, cross-subgroup
// softmax-state merge). GEMM/CSR/casts unchanged from R4.
// N=50000, E=800000, H=2, C_IN=256, C1=64, C2=128.

#define NEG_SLOPE 0.2f

typedef _Float16 f16x8 __attribute__((ext_vector_type(8)));
typedef _Float16 f16x4 __attribute__((ext_vector_type(4)));
typedef _Float16 f16x2 __attribute__((ext_vector_type(2)));
typedef float f32x4 __attribute__((ext_vector_type(4)));

// x += dpp_perm(x). 0xB1=quad xor1, 0x4E=quad xor2, 0x141=row_half_mirror.
#define DPPADD(x, CTRL)                                                        \
  do {                                                                         \
    int _y = __builtin_amdgcn_update_dpp(0, __float_as_int(x), CTRL, 0xf, 0xf, \
                                         true);                                \
    x += __int_as_float(_y);                                                   \
  } while (0)

// ---------------------------------------------------------------------------
__global__ __launch_bounds__(256) void cast_f2h(
    const float* __restrict__ src, _Float16* __restrict__ dst, int total4) {
  const int t = blockIdx.x * blockDim.x + threadIdx.x;
  if (t >= total4) return;
  const float4 v = *(const float4*)&src[(size_t)t * 4];
  f16x4 h;
  h[0] = (_Float16)v.x; h[1] = (_Float16)v.y; h[2] = (_Float16)v.z; h[3] = (_Float16)v.w;
  *(f16x4*)&dst[(size_t)t * 4] = h;
}

__global__ __launch_bounds__(256) void tcast_w(
    const float* __restrict__ Wl, const float* __restrict__ Wr,
    _Float16* __restrict__ Bt, int K, int NH) {
  const int t = blockIdx.x * blockDim.x + threadIdx.x;
  if (t >= 2 * NH * K) return;
  const int n = t / K, k = t - n * K;
  const float v = (n < NH) ? Wl[(size_t)k * NH + n] : Wr[(size_t)k * NH + (n - NH)];
  Bt[t] = (_Float16)v;
}

// ---------------------------------------------------------------------------
// C[M][NT](f16) = A[M][K](f16) @ Bt[NT][K]^T. 128x64 tile, BK=64, 4 waves.
__global__ __launch_bounds__(256) void hgemm_tn(
    const _Float16* __restrict__ A, const _Float16* __restrict__ Bt,
    _Float16* __restrict__ C, int M, int NT, int K) {
  constexpr int LDA = 88;
  __shared__ _Float16 As[128 * LDA];
  __shared__ _Float16 Bs[64 * LDA];
  const int bm = blockIdx.y * 128;
  const int bn = blockIdx.x * 64;
  const int tid = threadIdx.x;
  const int lane = tid & 63;
  const int wave = tid >> 6;
  const int wr = (wave >> 1) * 64;
  const int wc = (wave & 1) * 32;
  const int l15 = lane & 15;
  const int kq = (lane >> 4) * 8;
  f32x4 acc[4][2] = {};
  for (int k0 = 0; k0 < K; k0 += 64) {
    f16x8 a[4], b[2];
#pragma unroll
    for (int i = 0; i < 4; ++i) {
      const int c = tid + 256 * i;
      const int r = c >> 3, ks = (c & 7) * 8;
      const int row = bm + r;
      a[i] = (row < M) ? *(const f16x8*)&A[(size_t)row * K + k0 + ks] : f16x8{};
    }
#pragma unroll
    for (int i = 0; i < 2; ++i) {
      const int c = tid + 256 * i;
      const int r = c >> 3, ks = (c & 7) * 8;
      b[i] = *(const f16x8*)&Bt[(size_t)(bn + r) * K + k0 + ks];
    }
    __syncthreads();
#pragma unroll
    for (int i = 0; i < 4; ++i) {
      const int c = tid + 256 * i;
      const int r = c >> 3, ks = (c & 7) * 8;
      *(f16x8*)&As[r * LDA + ks] = a[i];
    }
#pragma unroll
    for (int i = 0; i < 2; ++i) {
      const int c = tid + 256 * i;
      const int r = c >> 3, ks = (c & 7) * 8;
      *(f16x8*)&Bs[r * LDA + ks] = b[i];
    }
    __syncthreads();
#pragma unroll
    for (int kk = 0; kk < 64; kk += 32) {
      f16x8 bf[2];
#pragma unroll
      for (int ni = 0; ni < 2; ++ni)
        bf[ni] = *(const f16x8*)&Bs[(wc + ni * 16 + l15) * LDA + kk + kq];
#pragma unroll
      for (int mi = 0; mi < 4; ++mi) {
        const f16x8 af = *(const f16x8*)&As[(wr + mi * 16 + l15) * LDA + kk + kq];
#pragma unroll
        for (int ni = 0; ni < 2; ++ni)
          acc[mi][ni] = __builtin_amdgcn_mfma_f32_16x16x32_f16(af, bf[ni], acc[mi][ni], 0, 0, 0);
      }
    }
  }
  const int crow0 = (lane >> 4) * 4;
#pragma unroll
  for (int mi = 0; mi < 4; ++mi) {
#pragma unroll
    for (int r = 0; r < 4; ++r) {
      const int row = bm + wr + mi * 16 + crow0 + r;
      if (row < M) {
#pragma unroll
        for (int ni = 0; ni < 2; ++ni)
          C[(size_t)row * NT + bn + wc + ni * 16 + l15] = (_Float16)acc[mi][ni][r];
      }
    }
  }
}

// ---------------------------------------------------------------------------
// CSR build (self-loops appended as (n->n)).
__global__ __launch_bounds__(256) void csr_count(
    const int* __restrict__ ei, int E, int EA, int* __restrict__ cnt) {
  const int i = blockIdx.x * blockDim.x + threadIdx.x;
  if (i >= EA) return;
  const int dst = (i < E) ? ei[E + i] : (i - E);
  atomicAdd(&cnt[dst], 1);
}

__global__ __launch_bounds__(256) void scan_block(
    const int* __restrict__ cnt, int* __restrict__ excl,
    int* __restrict__ bsum, int n) {
  __shared__ int s[256];
  const int tid = threadIdx.x;
  const int i = blockIdx.x * 256 + tid;
  const int v = (i < n) ? cnt[i] : 0;
  s[tid] = v;
  __syncthreads();
  for (int off = 1; off < 256; off <<= 1) {
    const int t = (tid >= off) ? s[tid - off] : 0;
    __syncthreads();
    s[tid] += t;
    __syncthreads();
  }
  if (i < n) excl[i] = s[tid] - v;
  if (tid == 255) bsum[blockIdx.x] = s[255];
}

__global__ __launch_bounds__(256) void scan_top(
    const int* __restrict__ bsum, int* __restrict__ bofs, int nb) {
  __shared__ int s[256];
  const int tid = threadIdx.x;
  const int v = (tid < nb) ? bsum[tid] : 0;
  s[tid] = v;
  __syncthreads();
  for (int off = 1; off < 256; off <<= 1) {
    const int t = (tid >= off) ? s[tid - off] : 0;
    __syncthreads();
    s[tid] += t;
    __syncthreads();
  }
  if (tid < nb) bofs[tid] = s[tid] - v;
}

__global__ __launch_bounds__(256) void scan_add(
    int* __restrict__ rowptr, const int* __restrict__ bofs, int n, int EA) {
  const int i = blockIdx.x * blockDim.x + threadIdx.x;
  if (i < n) rowptr[i] += bofs[i >> 8];
  if (i == 0) rowptr[n] = EA;
}

__global__ __launch_bounds__(256) void csr_fill(
    const int* __restrict__ ei, int E, int EA,
    const int* __restrict__ rowptr, int* __restrict__ wo,
    int* __restrict__ col) {
  const int i = blockIdx.x * blockDim.x + threadIdx.x;
  if (i >= EA) return;
  int src, dst;
  if (i < E) { src = ei[i]; dst = ei[E + i]; } else { src = dst = i - E; }
  const int pos = atomicAdd(&wo[dst], 1);
  col[rowptr[dst] + pos] = src;
}

// ---------------------------------------------------------------------------
// Fused per-node GATv2, 4 edges per wave.
// Wave = 1 node. sub = lane>>4 (edge subgroup), li = lane&15 (channel lane).
// Each lane holds VV = 2C/16 channels (co = li*VV); lanes 0-7 of each
// subgroup = head0 channels, 8-15 = head1 (since head boundary = C = 8*VV).
// Subgroup g processes edges e0+g, e0+g+4, ... with its own online softmax
// (m,l,O); states merged across subgroups at the end.
template <int C, int LOGS, int VV, bool RELU, bool OUT16>
__global__ __launch_bounds__(256) void fused_gat_h(
    const int* __restrict__ rowptr, const int* __restrict__ col,
    const _Float16* __restrict__ feat, const float* __restrict__ att,
    const float* __restrict__ bias, _Float16* __restrict__ out16,
    float* __restrict__ out32, int N) {
  constexpr int P = VV / 2;
  typedef _Float16 hv __attribute__((ext_vector_type(VV)));
  const int n = blockIdx.x * 4 + (threadIdx.x >> 6);
  if (n >= N) return;
  const int lane = threadIdx.x & 63;
  const int sub = lane >> 4;
  const int li = lane & 15;
  const int co = li * VV;                   // channel offset in [0, 2C)

  f16x2 xr2[P], at2[P];
  float O[VV];
  {
    const int base = (n << LOGS) + 2 * C + co;
#pragma unroll
    for (int p = 0; p < P; ++p) xr2[p] = *(const f16x2*)&feat[base + 2 * p];
#pragma unroll
    for (int p = 0; p < P; ++p)
      at2[p] = f16x2{(_Float16)att[co + 2 * p], (_Float16)att[co + 2 * p + 1]};
#pragma unroll
    for (int j = 0; j < VV; ++j) O[j] = 0.f;
  }
  float m = -1e30f, l = 0.f;
  const int e0 = rowptr[n], e1 = rowptr[n + 1];
  const int iters = (e1 - e0 + 3) >> 2;

  const f16x2 z2 = f16x2{(_Float16)0.f, (_Float16)0.f};
  const f16x2 ns2 = f16x2{(_Float16)NEG_SLOPE, (_Float16)NEG_SLOPE};

  int e = e0 + sub;
  {
    const int es = (e < e1) ? e : (e1 - 1);
    // fallthrough handled below
  }
  int cc = col[(e < e1) ? e : (e1 - 1)];
  hv cur = *(const hv*)&feat[(cc << LOGS) + co];

  for (int i = 0; i < iters; ++i) {
    const bool valid = e < e1;
    const int en = e + 4;
    const int cn = col[(en < e1) ? en : (e1 - 1)];
    const hv nxt = *(const hv*)&feat[(cn << LOGS) + co];   // prefetch
    // logit partial dot over my VV channels
    float pacc = 0.f;
#pragma unroll
    for (int p = 0; p < P; ++p) {
      const f16x2 c2 = f16x2{cur[2 * p], cur[2 * p + 1]};
      const f16x2 s = c2 + xr2[p];
      const f16x2 mx = __builtin_elementwise_max(s, z2);
      const f16x2 mn = __builtin_elementwise_min(s, z2);
      const f16x2 lk = mn * ns2 + mx;
      pacc = __builtin_amdgcn_fdot2(lk, at2[p], pacc, false);
    }
    // reduce across the 8 lanes of my head-half (within 16-lane subgroup)
    DPPADD(pacc, 0xB1);    // quad xor1
    DPPADD(pacc, 0x4E);    // quad xor2
    DPPADD(pacc, 0x141);   // row_half_mirror: adds the other quad in my 8
    if (!valid) pacc = -INFINITY;
    // online softmax with defer-max (THR=8); w masked to 0 when invalid
    if (__any(pacc - m > 8.f)) {
      const float mn2 = fmaxf(m, pacc);
      const float scale = __expf(m - mn2);
      const float w = valid ? __expf(pacc - mn2) : 0.f;
      l = l * scale + w;
#pragma unroll
      for (int j = 0; j < VV; ++j) O[j] = O[j] * scale + w * (float)cur[j];
      m = mn2;
    } else {
      const float w = valid ? __expf(pacc - m) : 0.f;
      l += w;
#pragma unroll
      for (int j = 0; j < VV; ++j) O[j] += w * (float)cur[j];
    }
    cur = nxt;
    e = en;
  }

  // merge the 4 subgroup softmax states (lanes l, l^16, l^32, l^48)
#pragma unroll
  for (int off = 16; off <= 32; off <<= 1) {
    const float m2 = __shfl_xor(m, off, 64);
    const float l2 = __shfl_xor(l, off, 64);
    const float mn = fmaxf(m, m2);
    const float s1 = __expf(m - mn);
    const float s2 = __expf(m2 - mn);
    l = l * s1 + l2 * s2;
#pragma unroll
    for (int j = 0; j < VV; ++j)
      O[j] = O[j] * s1 + __shfl_xor(O[j], off, 64) * s2;
    m = mn;
  }

  const float inv = 1.f / l;
  if constexpr (OUT16) {
    // VV=8: each subgroup writes 2 of my 8 channels -> f16x2 store
    const int j0 = sub * 2;
    f16x2 o;
    float v0 = O[j0] * inv + bias[co + j0];
    float v1 = O[j0 + 1] * inv + bias[co + j0 + 1];
    if constexpr (RELU) { v0 = fmaxf(v0, 0.f); v1 = fmaxf(v1, 0.f); }
    o[0] = (_Float16)v0; o[1] = (_Float16)v1;
    *(f16x2*)&out16[n * (2 * C) + co + j0] = o;
  } else {
    // VV=16: each subgroup writes 4 of my 16 channels -> float4 store
    const int j0 = sub * 4;
    float4 o;
    o.x = O[j0 + 0] * inv + bias[co + j0 + 0];
    o.y = O[j0 + 1] * inv + bias[co + j0 + 1];
    o.z = O[j0 + 2] * inv + bias[co + j0 + 2];
    o.w = O[j0 + 3] * inv + bias[co + j0 + 3];
    *(float4*)&out32[(size_t)n * (2 * C) + co + j0] = o;
  }
}

// ---------------------------------------------------------------------------
extern "C" void kernel_launch(void* const* d_in, const int* in_sizes, int n_in,
                              void* d_out, int out_size, void* d_ws, size_t ws_size,
                              hipStream_t stream) {
  const float* x    = (const float*)d_in[0];
  const int*   ei   = (const int*)d_in[1];
  const float* Wl0  = (const float*)d_in[2];
  const float* Wr0  = (const float*)d_in[3];
  const float* att0 = (const float*)d_in[4];
  const float* b0   = (const float*)d_in[5];
  const float* Wl1  = (const float*)d_in[6];
  const float* Wr1  = (const float*)d_in[7];
  const float* att1 = (const float*)d_in[8];
  const float* b1   = (const float*)d_in[9];
  float* out = (float*)d_out;

  const int N  = in_sizes[0] / 256;
  const int E  = in_sizes[1] / 2;
  const int EA = E + N;

  _Float16* hw    = (_Float16*)d_ws;
  _Float16* feat0 = hw;                        // N x 256 (overlapped by feat1)
  _Float16* feat1 = hw;                        // N x 512
  _Float16* ha    = hw + (size_t)N * 512;      // N x 128 (L0 out, f16)
  _Float16* xa    = hw + (size_t)N * 640;      // N x 256 (x in f16)
  _Float16* Bt0   = hw + (size_t)N * 896;      // 256 x 256
  _Float16* Bt1   = Bt0 + 65536;               // 512 x 128
  int* rowptr = (int*)(Bt1 + 65536);
  int* cnt    = rowptr + (N + 1);
  int* wo     = cnt + N;
  int* bsum   = wo + N;
  int* bofs   = bsum + 256;
  int* col    = bofs + 256;

  const dim3 blk(256);
  const int gEA   = (EA + 255) / 256;
  const int gScan = (N + 255) / 256;
  const int gM    = (N + 127) / 128;
  const int gNode = (N + 3) / 4;

  cast_f2h<<<(N * 64 + 255) / 256, blk, 0, stream>>>(x, xa, N * 64);
  tcast_w<<<(65536 + 255) / 256, blk, 0, stream>>>(Wl0, Wr0, Bt0, 256, 128);
  tcast_w<<<(65536 + 255) / 256, blk, 0, stream>>>(Wl1, Wr1, Bt1, 128, 256);

  hipMemsetAsync(cnt, 0, (size_t)N * 4, stream);
  hipMemsetAsync(wo, 0, (size_t)N * 4, stream);
  csr_count<<<gEA, blk, 0, stream>>>(ei, E, EA, cnt);
  scan_block<<<gScan, blk, 0, stream>>>(cnt, rowptr, bsum, N);
  scan_top<<<1, blk, 0, stream>>>(bsum, bofs, gScan);
  scan_add<<<gScan, blk, 0, stream>>>(rowptr, bofs, N, EA);
  csr_fill<<<gEA, blk, 0, stream>>>(ei, E, EA, rowptr, wo, col);

  // Layer 0  (C=64, stride 256 halves -> LOGS=8, VV = 128/16 = 8)
  hgemm_tn<<<dim3(4, gM), blk, 0, stream>>>(xa, Bt0, feat0, N, 256, 256);
  fused_gat_h<64, 8, 8, true, true><<<gNode, blk, 0, stream>>>(
      rowptr, col, feat0, att0, b0, ha, nullptr, N);

  // Layer 1  (C=128, stride 512 halves -> LOGS=9, VV = 256/16 = 16)
  hgemm_tn<<<dim3(8, gM), blk, 0, stream>>>(ha, Bt1, feat1, N, 512, 128);
  fused_gat_h<128, 9, 16, false, false><<<gNode, blk, 0, stream>>>(
      rowptr, col, feat1, att1, b1, nullptr, out, N);
}